// Round 4
// baseline (82.768 us; speedup 1.0000x reference)
//
#include <hip/hip_runtime.h>

namespace {
constexpr int NA     = 128;
constexpr int NC2    = NA * (NA - 1) / 2;     // 8128
constexpr int NT     = NA / 4;                // 32 chunks of 4 atoms
constexpr int NTILES = NT * (NT + 1) / 2;     // 528 lower-tri 4x4 tiles
constexpr float SCALE = 627.5095f * 0.529177f / 100.0f;  // AU2KCALMOLA/MAX_NRF

typedef float v4 __attribute__((ext_vector_type(4)));
struct __attribute__((packed)) v4p { v4 v; };  // 4B-alignable 16B vector
}

// One block per batch row. Pair triangle tiled into 528 4x4 tiles over
// 4-atom chunks (I,J), J<=I. Each thread owns one tile: 6 ds_read_b128
// (SoA x/y/z for the i-chunk and j-chunk) -> 16 outputs, vs 32 reads/16
// outputs in the per-pair scheme. SoA chunk reads are aligned 16B at
// lane-stride 16B = canonical conflict-free LDS pattern; i-chunk reads are
// near-uniform -> broadcast. Outputs for tile row i land at tri(i)+4J --
// contiguous 16B segments, stored as unaligned-tolerant v4 (tri(i) is not
// a multiple of 4). Diagonal tiles (I==J, 32 of 528) use a guarded scalar
// path (6 of 16 entries valid: j < i).
__global__ __launch_bounds__(256) void nrf_kernel(
    const float* __restrict__ coords,
    const float* __restrict__ atoms,
    float* __restrict__ out)
{
    __shared__ float sx[NA], sy[NA], sz[NA];
    const int b   = blockIdx.x;
    const int tid = threadIdx.x;

    // Stage coords[b] (384 contiguous floats) -> SoA.
    const float* cb = coords + (size_t)b * (NA * 3);
    for (int k = tid; k < NA * 3; k += 256) {
        int atom = k / 3;                 // constant div -> magic mul
        int comp = k - atom * 3;
        float v = cb[k];
        if (comp == 0)      sx[atom] = v;
        else if (comp == 1) sy[atom] = v;
        else                sz[atom] = v;
    }
    __syncthreads();

    float* outb = out + (size_t)b * NC2;

    for (int T = tid; T < NTILES; T += 256) {
        // decode T -> (I,J): T = I(I+1)/2 + J, 0<=J<=I<32.
        // f32 sqrt exact enough here (values <= 4225); +-1 fixup.
        int I   = (int)((sqrtf((float)(8 * T + 9)) - 1.0f) * 0.5f);
        int trI = (I * (I + 1)) >> 1;
        if (trI > T)           { trI -= I; --I; }        // tri2(I-1)=tri2(I)-I
        if (trI + I + 1 <= T)  { trI += I + 1; ++I; }    // tri2(I+1)=tri2(I)+I+1
        const int J = T - trI;

        const v4 xi = *(const v4*)&sx[4 * I];   // near-uniform -> broadcast
        const v4 yi = *(const v4*)&sy[4 * I];
        const v4 zi = *(const v4*)&sz[4 * I];
        const v4 xj = *(const v4*)&sx[4 * J];   // lane-stride 16B -> no conflict
        const v4 yj = *(const v4*)&sy[4 * J];
        const v4 zj = *(const v4*)&sz[4 * J];

        if (I != J) {
            #pragma unroll
            for (int k = 0; k < 4; ++k) {
                const int i  = 4 * I + k;
                const int p0 = ((i * (i - 1)) >> 1) + 4 * J;  // all 4 valid, in-bounds
                const v4 av = ((const v4p*)&atoms[p0])->v;
                v4 res;
                #pragma unroll
                for (int m = 0; m < 4; ++m) {
                    float dx = xi[k] - xj[m];
                    float dy = yi[k] - yj[m];
                    float dz = zi[k] - zj[m];
                    float d2 = dx * dx + dy * dy + dz * dz;
                    // ref: 1/(sqrt(d2))^2 == 1/d2 within ~2 ulp; rcp is 1 ulp
                    res[m] = av[m] * SCALE * __builtin_amdgcn_rcpf(d2);
                }
                ((v4p*)&outb[p0])->v = res;
            }
        } else {
            // diagonal tile: row k has k valid entries (j = 4I+m, m<k)
            #pragma unroll
            for (int k = 1; k < 4; ++k) {
                const int i  = 4 * I + k;
                const int p0 = ((i * (i - 1)) >> 1) + 4 * I;
                #pragma unroll
                for (int m = 0; m < 4; ++m) {
                    if (m < k) {
                        float dx = xi[k] - xj[m];
                        float dy = yi[k] - yj[m];
                        float dz = zi[k] - zj[m];
                        float d2 = dx * dx + dy * dy + dz * dz;
                        outb[p0 + m] = atoms[p0 + m] * SCALE *
                                       __builtin_amdgcn_rcpf(d2);
                    }
                }
            }
        }
    }
}

extern "C" void kernel_launch(void* const* d_in, const int* in_sizes, int n_in,
                              void* d_out, int out_size, void* d_ws, size_t ws_size,
                              hipStream_t stream)
{
    const float* coords = (const float*)d_in[0];
    const float* atoms  = (const float*)d_in[1];
    float*       out    = (float*)d_out;
    const int batch = in_sizes[0] / (NA * 3);    // 2048
    nrf_kernel<<<batch, 256, 0, stream>>>(coords, atoms, out);
}

// Round 5
// 82.549 us; speedup vs baseline: 1.0026x; 1.0026x over previous
//
#include <hip/hip_runtime.h>

namespace {
constexpr int NA  = 128;
constexpr int NC2 = NA * (NA - 1) / 2;   // 8128
constexpr int NQ  = NC2 / 4;             // 2032 float4 outputs per batch row
constexpr float SCALE = 627.5095f * 0.529177f / 100.0f;  // AU2KCALMOLA/MAX_NRF

typedef float v4 __attribute__((ext_vector_type(4)));

// LDS swizzle: breaks the stride-4 bank cycle of lane-consecutive j reads
// (bank = j%32 with j-stride 4 across lanes would be 8-way conflicted;
// j+(j>>3) spreads it to <=4-way, which costs ~1.6x on the LDS pipe --
// still far under the store-bandwidth floor).
__device__ __forceinline__ int swz(int j) { return j + (j >> 3); }
}

// One block per batch row. Thread owns 4 CONSECUTIVE flat pair indices
// p=4q..4q+3, so atoms loads and out stores are ALIGNED dwordx4 with
// lane-consecutive addresses -- byte-identical to the pattern the harness
// fill sustains 6 TB/s with. Pair (i,j) decoded once per 4 outputs via f32
// sqrt (exact to +-1 for p<8128, two-sided fixup), then advanced branchlessly
// (j+1==i -> next row). Coords in swizzled SoA LDS.
__global__ __launch_bounds__(256) void nrf_kernel(
    const float* __restrict__ coords,
    const float* __restrict__ atoms,
    float* __restrict__ out)
{
    __shared__ float sx[NA + NA / 8], sy[NA + NA / 8], sz[NA + NA / 8];
    const int b   = blockIdx.x;
    const int tid = threadIdx.x;

    // Stage coords[b] (384 contiguous floats) -> swizzled SoA.
    const float* cb = coords + (size_t)b * (NA * 3);
    for (int k = tid; k < NA * 3; k += 256) {
        int atom = k / 3;                 // constant div -> magic mul
        int comp = k - atom * 3;
        float v = cb[k];
        int s = swz(atom);
        if (comp == 0)      sx[s] = v;
        else if (comp == 1) sy[s] = v;
        else                sz[s] = v;
    }
    __syncthreads();

    const v4* a4 = (const v4*)atoms;
    v4*       o4 = (v4*)(out + (size_t)b * NC2);   // NC2*4 % 16 == 0 -> aligned

    for (int q = tid; q < NQ; q += 256) {
        int p = 4 * q;
        // decode p -> (i,j): i = floor((1+sqrt(8p+1))/2), +-1 fixup
        int i = (int)((1.0f + sqrtf((float)(8 * p + 1))) * 0.5f);
        int t = (i * (i - 1)) >> 1;       // tri(i)
        if (t > p)      { --i; t -= i; }  // tri(i-1) = tri(i) - new_i
        if (t + i <= p) { t += i; ++i; }  // tri(i+1) = tri(i) + old_i
        int j = p - t;

        v4 av = a4[q];                    // aligned dwordx4, lane-consecutive
        v4 res;
        #pragma unroll
        for (int k = 0; k < 4; ++k) {
            int si = swz(i), sj = swz(j);
            float dx = sx[si] - sx[sj];   // si near-uniform -> broadcast
            float dy = sy[si] - sy[sj];   // sj swizzled -> <=4-way
            float dz = sz[si] - sz[sj];
            float d2 = dx * dx + dy * dy + dz * dz;
            // ref: 1/(sqrt(d2))^2 == 1/d2 within ~2 ulp; v_rcp_f32 is 1 ulp
            res[k] = av[k] * SCALE * __builtin_amdgcn_rcpf(d2);
            ++j; if (j == i) { ++i; j = 0; }   // advance (cndmask, no branch)
        }
        o4[q] = res;                      // aligned dwordx4, lane-consecutive
    }
}

extern "C" void kernel_launch(void* const* d_in, const int* in_sizes, int n_in,
                              void* d_out, int out_size, void* d_ws, size_t ws_size,
                              hipStream_t stream)
{
    const float* coords = (const float*)d_in[0];
    const float* atoms  = (const float*)d_in[1];
    float*       out    = (float*)d_out;
    const int batch = in_sizes[0] / (NA * 3);    // 2048
    nrf_kernel<<<batch, 256, 0, stream>>>(coords, atoms, out);
}